// Round 7
// baseline (163.285 us; speedup 1.0000x reference)
//
#include <hip/hip_runtime.h>
#include <math.h>

// Problem constants: B=32, C=D=64, H=W=32
#define NPTS 32768      // B*H*W
#define KCB  1024
#define DIM  64
#define HW   1024
#define CHW  65536
#define PT   128        // points per block (k_dist)
#define RWIN 2          // OT band radius (validated R3..R6: absmax 0.0)

__device__ __forceinline__ float block_sum(float v, float* scratch) {
  #pragma unroll
  for (int o = 32; o > 0; o >>= 1) v += __shfl_down(v, o, 64);
  int wid  = threadIdx.x >> 6;
  int lane = threadIdx.x & 63;
  __syncthreads();
  if (lane == 0) scratch[wid] = v;
  __syncthreads();
  float s = 0.f;
  int nw = blockDim.x >> 6;
  for (int w = 0; w < nw; ++w) s += scratch[w];
  return s;
}

// K1: fully-fused distance GEMM. 512 blocks (256 pt-tiles x 2 code-halves), 2/CU.
// - register-prefetch double-buffer: phase p+1's code rows loaded during compute(p)
// - cnorm from staging regs (same f4 fmaf chain as before -> bit-exact)
// - sumx in-block from lp (exact c-ordered chain, same values as global path)
// - zeroes hist/out-accumulators (stream order protects later dispatches)
// Winner via packed-u64 global atomicMin (ws poison 0xAA.. > any real packed value).
__global__ __launch_bounds__(256, 2) void k_dist(const float* __restrict__ x,
                                                 const float* __restrict__ cb,
                                                 unsigned long long* __restrict__ pmin,
                                                 int* __restrict__ hist,
                                                 float* __restrict__ out) {
  __shared__ __align__(16) float lp[DIM][132];   // points, split lo/hi cols, pad->2-way
  __shared__ __align__(16) float lc[32][256];    // code chunk (32 dims), identity cols
  __shared__ float s_cn[256];                    // ||code||^2 for current ct
  __shared__ float s_sx[PT];                     // ||x||^2 per point
  int tid = threadIdx.x;
  int t   = blockIdx.x;
  int kb  = blockIdx.y * 512;
  int n0  = t * PT;
  int b   = n0 >> 10;
  int hw0 = n0 & 1023;

  // zero duties (consumed by later dispatches only)
  if (blockIdx.y == 0 && t < 4) hist[t * 256 + tid] = 0;
  if (blockIdx.y == 0 && t == 0 && tid < 2) out[2097152 + tid] = 0.f;

  // stage points: f4 of pts 4*p4..4*p4+3 (dim crow-major) -> col (p4&1)*64+(p4>>1)*4
  {
    const float* xb = x + b * CHW + hw0;
    int crow = tid >> 5, p4 = tid & 31;
    int col0 = (p4 & 1) * 64 + (p4 >> 1) * 4;
    #pragma unroll
    for (int i = 0; i < 8; ++i) {
      int c = i * 8 + crow;
      *(float4*)&lp[c][col0] = *(const float4*)(xb + c * HW + p4 * 4);
    }
  }

  int tx = tid & 15, ty = tid >> 4;

  // prefetch phase 0 (ct0, dims 0..31 of code kb+tid)
  float4 pf[8];
  {
    const float4* row = (const float4*)(cb + (kb + tid) * DIM);
    #pragma unroll
    for (int i = 0; i < 8; ++i) pf[i] = row[i];
  }

  float best[8];
  int   bidx[8];
  #pragma unroll
  for (int pp = 0; pp < 8; ++pp) { best[pp] = 3.4e38f; bidx[pp] = 0; }

  float acc[8][16];
  float cn_own = 0.f;

  for (int ph = 0; ph < 4; ++ph) {
    int ct = ph >> 1, dh = ph & 1;
    int k0 = kb + ct * 256;

    if (dh == 0) {
      #pragma unroll
      for (int pp = 0; pp < 8; ++pp)
        #pragma unroll
        for (int cc = 0; cc < 16; ++cc) acc[pp][cc] = 0.f;
    }

    __syncthreads();   // previous phase's lc readers done (ph0: lp stores ordered too)
    // store pf -> lc column tid (bank=lane: 2-way free)
    #pragma unroll
    for (int i = 0; i < 8; ++i) {
      int d = i * 4;
      lc[d + 0][tid] = pf[i].x;
      lc[d + 1][tid] = pf[i].y;
      lc[d + 2][tid] = pf[i].z;
      lc[d + 3][tid] = pf[i].w;
    }
    // cnorm partial from regs — same f4 x,y,z,w fmaf chain, d ascending (bit-exact)
    if (dh == 0) cn_own = 0.f;
    #pragma unroll
    for (int i = 0; i < 8; ++i) {
      cn_own = fmaf(pf[i].x, pf[i].x, cn_own);
      cn_own = fmaf(pf[i].y, pf[i].y, cn_own);
      cn_own = fmaf(pf[i].z, pf[i].z, cn_own);
      cn_own = fmaf(pf[i].w, pf[i].w, cn_own);
    }
    if (dh == 1) s_cn[tid] = cn_own;
    // prefetch next phase while this one computes
    if (ph < 3) {
      int np = ph + 1;
      const float4* row =
          (const float4*)(cb + (kb + (np >> 1) * 256 + tid) * DIM) + (np & 1) * 8;
      #pragma unroll
      for (int i = 0; i < 8; ++i) pf[i] = row[i];
    }
    __syncthreads();   // lc visible

    if (ph == 0 && tid < PT) {
      // sumx for point tid: exact c-ordered scalar fmaf chain (values == global x)
      int p = tid;
      int col = ((p >> 2) & 1) * 64 + (p >> 3) * 4 + (p & 3);
      float s = 0.f;
      #pragma unroll
      for (int c = 0; c < DIM; ++c) { float v = lp[c][col]; s = fmaf(v, v, s); }
      s_sx[p] = s;
    }

    int dbase = dh * 32;
    #pragma unroll 4
    for (int dd = 0; dd < 32; ++dd) {
      int d = dbase + dd;
      float4 a0 = *(const float4*)&lp[d][4 * ty];        // pts ty*8..+3
      float4 a1 = *(const float4*)&lp[d][64 + 4 * ty];   // pts ty*8+4..+7
      float4 b0 = *(const float4*)&lc[dd][4 * tx];          // codes k0+4tx..
      float4 b1 = *(const float4*)&lc[dd][64 + 4 * tx];
      float4 b2 = *(const float4*)&lc[dd][128 + 4 * tx];
      float4 b3 = *(const float4*)&lc[dd][192 + 4 * tx];
      float av[8]  = {a0.x, a0.y, a0.z, a0.w, a1.x, a1.y, a1.z, a1.w};
      float bv[16] = {b0.x, b0.y, b0.z, b0.w, b1.x, b1.y, b1.z, b1.w,
                      b2.x, b2.y, b2.z, b2.w, b3.x, b3.y, b3.z, b3.w};
      #pragma unroll
      for (int pp = 0; pp < 8; ++pp) {
        float a = av[pp];
        #pragma unroll
        for (int cc = 0; cc < 16; ++cc)
          acc[pp][cc] = fmaf(a, bv[cc], acc[pp][cc]);   // d-ordered chain == np
      }
    }

    if (dh == 1) {
      // fold this ct (k = k0 + 64*q + 4*tx + e, ascending -> first-min)
      float sxl[8];
      #pragma unroll
      for (int pp = 0; pp < 8; ++pp) sxl[pp] = s_sx[ty * 8 + pp];
      float cn[16];
      #pragma unroll
      for (int q = 0; q < 4; ++q) {
        float4 c4 = *(const float4*)&s_cn[64 * q + 4 * tx];
        cn[q*4+0] = c4.x; cn[q*4+1] = c4.y; cn[q*4+2] = c4.z; cn[q*4+3] = c4.w;
      }
      #pragma unroll
      for (int pp = 0; pp < 8; ++pp) {
        #pragma unroll
        for (int cc = 0; cc < 16; ++cc) {
          // reference fp32 rounding: (||x||^2 + ||c||^2) - 2*x.c
          float dist = (sxl[pp] + cn[cc]) - 2.0f * acc[pp][cc];
          int   k    = k0 + 64 * (cc >> 2) + 4 * tx + (cc & 3);
          if (dist < best[pp]) { best[pp] = dist; bidx[pp] = k; }
        }
      }
    }
  }

  // cross-tx argmin (16-lane groups), then cross-block via u64 atomicMin.
  #pragma unroll
  for (int pp = 0; pp < 8; ++pp) {
    unsigned long long pk =
        ((unsigned long long)__float_as_uint(best[pp]) << 32) | (unsigned)bidx[pp];
    #pragma unroll
    for (int m = 1; m < 16; m <<= 1) {
      unsigned long long o = __shfl_xor(pk, m, 64);
      pk = (o < pk) ? o : pk;
    }
    if (tx == 0) atomicMin(&pmin[n0 + ty * 8 + pp], pk);
  }
}

// K2: gather + straight-through write + commit-mse partial + hist count.
// 256 blocks x 128 threads: full-CU coverage, one point per thread.
__global__ __launch_bounds__(128) void k_fin(const float* __restrict__ x,
                                             const float* __restrict__ cb,
                                             const unsigned long long* __restrict__ pmin,
                                             int* __restrict__ hist,
                                             float* __restrict__ out) {
  __shared__ float scratch[2];
  int n = blockIdx.x * 128 + threadIdx.x;
  int bidx = (int)(pmin[n] & 0xffffffffull);
  atomicAdd(&hist[bidx], 1);
  int b = n >> 10, hw = n & 1023;
  const float* xp = x + b * CHW + hw;
  float* op = out + b * CHW + hw;
  const float4* q4 = (const float4*)(cb + bidx * DIM);
  float se = 0.f;
  #pragma unroll
  for (int d = 0; d < DIM/4; ++d) {
    float4 q = q4[d];
    float qq[4] = {q.x, q.y, q.z, q.w};
    #pragma unroll
    for (int j = 0; j < 4; ++j) {
      int c = 4 * d + j;
      float xv = xp[c * HW];
      float diff = qq[j] - xv;       // nq - x
      se += diff * diff;             // (clean_q - flat)^2 == commit mse
      op[c * HW] = xv + diff;        // x + stop_grad(nq - x), ref rounding
    }
  }
  float tot = block_sum(se, scratch);
  if (threadIdx.x == 0)
    atomicAdd(&out[2097152], tot * 1.25f * (1.0f / 2097152.0f));
}

// K3: prep + banded OT dual ascent + scalars. 256 threads x 4 elems (unchanged R6).
__global__ __launch_bounds__(256) void k_ot(const int* __restrict__ hist,
                                            float* __restrict__ out) {
  __shared__ __align__(16) float s_lt[KCB + 8], s_src[KCB + 8],
                                 s_phi[KCB + 8], s_lse[KCB + 8];
  __shared__ float scratch[4];
  int tid = threadIdx.x;
  int i0  = tid * 4;
  int sl0 = i0 + 4;          // arrays padded by 4 each side

  int4 hi4 = *(const int4*)(hist + i0);
  int  hi[4] = {hi4.x, hi4.y, hi4.z, hi4.w};
  float tj[4], hj[4];
  #pragma unroll
  for (int j = 0; j < 4; ++j) {
    float fi = (float)(i0 + j);
    float zz = (fi - 511.5f) / (1024.0f / 6.0f);
    tj[j] = expf(-0.5f * zz * zz);
    hj[j] = (float)hi[j] * (1.0f / 32768.0f);
  }
  float St = block_sum(tj[0] + tj[1] + tj[2] + tj[3], scratch);
  float tgt[4], ltw[4];
  float l2 = 0.f;
  #pragma unroll
  for (int j = 0; j < 4; ++j) { tgt[j] = fmaxf(tj[j] / fmaxf(St, 1e-12f), 1e-12f); l2 += tgt[j]; }
  float St2 = block_sum(l2, scratch);
  #pragma unroll
  for (int j = 0; j < 4; ++j) { tgt[j] = tgt[j] / St2; ltw[j] = logf(fmaxf(tgt[j], 1e-12f)); }

  float m1[4], srcw[4];
  float l3 = 0.f;
  #pragma unroll
  for (int j = 0; j < 4; ++j) { m1[j] = fmaxf(hj[j], 1e-12f); l3 += m1[j]; }
  float S1 = block_sum(l3, scratch);
  float l4 = 0.f;
  #pragma unroll
  for (int j = 0; j < 4; ++j) { srcw[j] = fmaxf(m1[j] / S1, 1e-12f); l4 += srcw[j]; }
  float S2 = block_sum(l4, scratch);
  float l5 = 0.f;
  #pragma unroll
  for (int j = 0; j < 4; ++j) { srcw[j] = srcw[j] / S2; l5 += hj[j] * logf(hj[j] + 1e-10f); }
  float ent = block_sum(l5, scratch);

  *(float4*)&s_lt[sl0]  = *(float4*)ltw;
  *(float4*)&s_src[sl0] = *(float4*)srcw;
  *(float4*)&s_phi[sl0] = make_float4(0.f, 0.f, 0.f, 0.f);
  *(float4*)&s_lse[sl0] = make_float4(0.f, 0.f, 0.f, 0.f);
  if (tid == 0) {    // pads: inert (validated R3..R6)
    #pragma unroll
    for (int p = 0; p < 4; ++p) {
      s_lt[p] = -100.f; s_src[p] = 0.f; s_phi[p] = 0.f; s_lse[p] = 0.f;
      s_lt[KCB+4+p] = -100.f; s_src[KCB+4+p] = 0.f; s_phi[KCB+4+p] = 0.f; s_lse[KCB+4+p] = 0.f;
    }
  }
  __syncthreads();

  float ws[12];
  #pragma unroll
  for (int m = 0; m < 3; ++m) *(float4*)&ws[m*4] = *(float4*)&s_src[i0 + m*4];

  float phi[4] = {0.f, 0.f, 0.f, 0.f};
  float lse[4];
  for (int it = 0; it <= 10; ++it) {
    float wl[12], wp[12];
    #pragma unroll
    for (int m = 0; m < 3; ++m) {
      *(float4*)&wl[m*4] = *(float4*)&s_lt[i0 + m*4];
      *(float4*)&wp[m*4] = *(float4*)&s_phi[i0 + m*4];
    }
    #pragma unroll
    for (int j = 0; j < 4; ++j) {
      float mx = -3.0e38f;
      float vv[5];
      #pragma unroll
      for (int q = 0; q < 5; ++q) {
        int m = j + q + 2;
        float a = wl[m] + (wp[m] - fabsf((float)(q - 2))) * 20.0f;
        vv[q] = a;
        mx = fmaxf(mx, a);
      }
      float ssum = 0.f;
      #pragma unroll
      for (int q = 0; q < 5; ++q) ssum += expf(vv[q] - mx);
      lse[j] = mx + logf(ssum);
    }
    *(float4*)&s_lse[sl0] = *(float4*)lse;
    __syncthreads();
    if (it == 10) break;

    float we[12];
    #pragma unroll
    for (int m = 0; m < 3; ++m) *(float4*)&we[m*4] = *(float4*)&s_lse[i0 + m*4];
    #pragma unroll
    for (int j = 0; j < 4; ++j) {
      float basej = ltw[j] + phi[j] * 20.0f;
      float cs = 0.f;
      #pragma unroll
      for (int q = 0; q < 5; ++q) {
        int m = j + q + 2;
        float a = basej - fabsf((float)(q - 2)) * 20.0f;
        cs += ws[m] * expf(a - we[m]);
      }
      phi[j] += 0.5f * (tgt[j] - cs);
    }
    *(float4*)&s_phi[sl0] = *(float4*)phi;
    __syncthreads();
  }

  float lo = 0.f;
  #pragma unroll
  for (int j = 0; j < 4; ++j) lo += srcw[j] * (-0.05f * lse[j]) + tgt[j] * phi[j];
  float ot = block_sum(lo, scratch);

  if (tid == 0) {
    atomicAdd(&out[2097152], ot);     // k_fin already added 1.25*mse
    out[2097153] = expf(-ent);        // perplexity
  }
}

extern "C" void kernel_launch(void* const* d_in, const int* in_sizes, int n_in,
                              void* d_out, int out_size, void* d_ws, size_t ws_size,
                              hipStream_t stream) {
  const float* x  = (const float*)d_in[0];   // [32,64,32,32]
  const float* cb = (const float*)d_in[1];   // [1024,64]
  float* out = (float*)d_out;                // quantized(2097152) | loss | perplexity

  int* hist = (int*)d_ws;                                        // 4 KB
  unsigned long long* pmin = (unsigned long long*)((char*)d_ws + 8192);  // 256 KB (poison-init OK)

  k_dist<<<dim3(NPTS / PT, 2), 256, 0, stream>>>(x, cb, pmin, hist, out);
  k_fin<<<NPTS / 128, 128, 0, stream>>>(x, cb, pmin, hist, out);
  k_ot<<<1, 256, 0, stream>>>(hist, out);
}

// Round 8
// 139.715 us; speedup vs baseline: 1.1687x; 1.1687x over previous
//
#include <hip/hip_runtime.h>
#include <math.h>

// Problem constants: B=32, C=D=64, H=W=32
#define NPTS 32768      // B*H*W
#define KCB  1024
#define DIM  64
#define HW   1024
#define CHW  65536
#define RWIN 2          // OT band radius (validated R3..R7: absmax 0.0)

typedef short  bf16x8 __attribute__((ext_vector_type(8)));
typedef float  f32x4  __attribute__((ext_vector_type(4)));

__device__ __forceinline__ unsigned short f2b_rne(float f) {
  unsigned u = __float_as_uint(f);
  unsigned r = 0x7FFFu + ((u >> 16) & 1u);
  return (unsigned short)((u + r) >> 16);
}

__device__ __forceinline__ float block_sum(float v, float* scratch) {
  #pragma unroll
  for (int o = 32; o > 0; o >>= 1) v += __shfl_down(v, o, 64);
  int wid  = threadIdx.x >> 6;
  int lane = threadIdx.x & 63;
  __syncthreads();
  if (lane == 0) scratch[wid] = v;
  __syncthreads();
  float s = 0.f;
  int nw = blockDim.x >> 6;
  for (int w = 0; w < nw; ++w) s += scratch[w];
  return s;
}

// K0: codebook -> bf16 hi/lo split arrays + cnorm (exact f4 fmaf chain) + hist zero.
__global__ __launch_bounds__(256) void k_cvt(const float* __restrict__ cb,
                                             unsigned short* __restrict__ cbh,
                                             unsigned short* __restrict__ cbl,
                                             float* __restrict__ cnorm,
                                             int* __restrict__ hist) {
  int k = blockIdx.x * 256 + threadIdx.x;   // grid 4x256 = 1024
  hist[k] = 0;
  const float4* row = (const float4*)(cb + k * DIM);
  float s = 0.f;
  unsigned short hb[64], lb[64];
  #pragma unroll
  for (int i = 0; i < 16; ++i) {
    float4 v = row[i];
    float vv[4] = {v.x, v.y, v.z, v.w};
    #pragma unroll
    for (int j = 0; j < 4; ++j) {
      float f = vv[j];
      s = fmaf(f, f, s);
      unsigned short h = f2b_rne(f);
      float hf = __uint_as_float(((unsigned)h) << 16);
      hb[i * 4 + j] = h;
      lb[i * 4 + j] = f2b_rne(f - hf);
    }
  }
  cnorm[k] = s;
  #pragma unroll
  for (int i = 0; i < 8; ++i) {
    *(bf16x8*)(cbh + k * 64 + i * 8) = *(bf16x8*)&hb[i * 8];
    *(bf16x8*)(cbl + k * 64 + i * 8) = *(bf16x8*)&lb[i * 8];
  }
}

// K1: MFMA distance GEMM + fused fin. 512 blocks x 64 pts, all 1024 codes.
// dot = hiA*hiB + hiA*loB + loA*hiB via mfma_f32_16x16x32_bf16 (err ~5e-7 vs
// top-2 gaps ~1e-4: flips rare and bounded by codebook diameter 0.002).
// A-frags (points) cached in regs all kernel; codes chunked 64-wide into LDS
// with 16-VGPR reg prefetch (R7 lesson: keep the held set small -> no spill).
__global__ __launch_bounds__(256, 2) void k_dist(const float* __restrict__ x,
                                                 const float* __restrict__ cb,
                                                 const unsigned short* __restrict__ cbh,
                                                 const unsigned short* __restrict__ cbl,
                                                 const float* __restrict__ cnorm,
                                                 int* __restrict__ hist,
                                                 float* __restrict__ msep,
                                                 float* __restrict__ out) {
  __shared__ unsigned short lph[64][72], lpl[64][72];  // points bf16 hi/lo, pad 72
  __shared__ float lpf[64][64];                        // exact f32 x tile [c][p]
  __shared__ unsigned short lch[64][72], lcl[64][72];  // code chunk bf16 hi/lo
  __shared__ float s_cn[KCB];
  __shared__ float s_sx[64];
  __shared__ float s_part[4][64];
  __shared__ int   s_bd[64];
  __shared__ float scratch[4];

  int tid = threadIdx.x;
  int t   = blockIdx.x;          // 512 blocks of 64 pts
  int n0  = t * 64;
  int b   = n0 >> 10;
  int hw0 = n0 & 1023;

  // cnorm -> LDS (coalesced f4)
  *(float4*)&s_cn[tid * 4] = *(const float4*)(cnorm + tid * 4);

  // point conversion: thread (p = tid&63, q4 = tid>>6) handles dims [16q4,16q4+16)
  {
    int p = tid & 63, q4 = tid >> 6;
    const float* xb = x + b * CHW + hw0 + p;
    float s = 0.f;
    unsigned short hb[16], lb[16];
    #pragma unroll
    for (int i = 0; i < 16; ++i) {
      int c = q4 * 16 + i;
      float f = xb[c * HW];                 // lanes consecutive p: coalesced
      s = fmaf(f, f, s);
      lpf[c][p] = f;
      unsigned short h = f2b_rne(f);
      float hf = __uint_as_float(((unsigned)h) << 16);
      hb[i] = h;
      lb[i] = f2b_rne(f - hf);
    }
    s_part[q4][p] = s;
    #pragma unroll
    for (int j = 0; j < 8; ++j) {           // packed b32 writes
      *(unsigned*)&lph[p][q4 * 16 + 2 * j] = (unsigned)hb[2*j] | ((unsigned)hb[2*j+1] << 16);
      *(unsigned*)&lpl[p][q4 * 16 + 2 * j] = (unsigned)lb[2*j] | ((unsigned)lb[2*j+1] << 16);
    }
  }
  __syncthreads();
  if (tid < 64)
    s_sx[tid] = ((s_part[0][tid] + s_part[1][tid]) + s_part[2][tid]) + s_part[3][tid];
  __syncthreads();

  int w = tid >> 6;          // wave -> pts 16w..16w+15 (one m-tile)
  int l = tid & 63;
  int c16 = l & 15, q = l >> 4;

  // A-frags: lane holds A[m=c16][k=8q+j] per K-step/hi-lo (verified layout, m89/m120)
  bf16x8 afh0, afh1, afl0, afl1;
  {
    int pt = w * 16 + c16;
    afh0 = *(const bf16x8*)&lph[pt][q * 8];
    afh1 = *(const bf16x8*)&lph[pt][32 + q * 8];
    afl0 = *(const bf16x8*)&lpl[pt][q * 8];
    afl1 = *(const bf16x8*)&lpl[pt][32 + q * 8];
  }
  // C-layout: col=l&15 (code), row=4q+r (pt) -> sumx for this lane's 4 rows
  float sx[4];
  #pragma unroll
  for (int r = 0; r < 4; ++r) sx[r] = s_sx[w * 16 + q * 4 + r];

  float best[4]; int bidx[4];
  #pragma unroll
  for (int r = 0; r < 4; ++r) { best[r] = 3.4e38f; bidx[r] = 0; }

  // prefetch chunk 0 (64 codes x 64 dims bf16 hi/lo = 16 KB; 16 VGPRs held)
  float4 pfh[2], pfl[2];
  {
    const float4* ph = (const float4*)cbh;
    const float4* pl = (const float4*)cbl;
    pfh[0] = ph[tid]; pfh[1] = ph[tid + 256];
    pfl[0] = pl[tid]; pfl[1] = pl[tid + 256];
  }

  for (int ch = 0; ch < 16; ++ch) {
    // write staged regs -> lc (b128, balanced banks)
    #pragma unroll
    for (int j = 0; j < 2; ++j) {
      int f4i  = tid + 256 * j;        // 0..511
      int code = f4i >> 3;             // 0..63
      int d0   = (f4i & 7) * 8;
      *(float4*)&lch[code][d0] = pfh[j];
      *(float4*)&lcl[code][d0] = pfl[j];
    }
    __syncthreads();
    if (ch < 15) {                     // prefetch next chunk during MFMAs
      const float4* ph = (const float4*)cbh + 512 * (ch + 1);
      const float4* pl = (const float4*)cbl + 512 * (ch + 1);
      pfh[0] = ph[tid]; pfh[1] = ph[tid + 256];
      pfl[0] = pl[tid]; pfl[1] = pl[tid + 256];
    }

    f32x4 acc[4];
    #pragma unroll
    for (int nt = 0; nt < 4; ++nt) acc[nt] = (f32x4){0.f, 0.f, 0.f, 0.f};
    #pragma unroll
    for (int nt = 0; nt < 4; ++nt) {
      int cc = nt * 16 + c16;          // B: lane holds B[k=8q+j][n=c16] = code row dims
      bf16x8 bh0 = *(const bf16x8*)&lch[cc][q * 8];
      bf16x8 bh1 = *(const bf16x8*)&lch[cc][32 + q * 8];
      bf16x8 bl0 = *(const bf16x8*)&lcl[cc][q * 8];
      bf16x8 bl1 = *(const bf16x8*)&lcl[cc][32 + q * 8];
      acc[nt] = __builtin_amdgcn_mfma_f32_16x16x32_bf16(afh0, bh0, acc[nt], 0, 0, 0);
      acc[nt] = __builtin_amdgcn_mfma_f32_16x16x32_bf16(afh0, bl0, acc[nt], 0, 0, 0);
      acc[nt] = __builtin_amdgcn_mfma_f32_16x16x32_bf16(afl0, bh0, acc[nt], 0, 0, 0);
      acc[nt] = __builtin_amdgcn_mfma_f32_16x16x32_bf16(afh1, bh1, acc[nt], 0, 0, 0);
      acc[nt] = __builtin_amdgcn_mfma_f32_16x16x32_bf16(afh1, bl1, acc[nt], 0, 0, 0);
      acc[nt] = __builtin_amdgcn_mfma_f32_16x16x32_bf16(afl1, bh1, acc[nt], 0, 0, 0);
    }
    // fold chunk into argmin (k ascending -> first-min)
    #pragma unroll
    for (int nt = 0; nt < 4; ++nt) {
      int kk = ch * 64 + nt * 16 + c16;
      float cnv = s_cn[kk];
      #pragma unroll
      for (int r = 0; r < 4; ++r) {
        float dist = (sx[r] + cnv) - 2.0f * acc[nt][r];
        if (dist < best[r]) { best[r] = dist; bidx[r] = kk; }
      }
    }
    __syncthreads();                   // readers done before next chunk's writes
  }

  // cross-col-lane argmin: 16 lanes (c16 group) share each (q,r) point
  #pragma unroll
  for (int r = 0; r < 4; ++r) {
    unsigned long long pk =
        ((unsigned long long)__float_as_uint(best[r]) << 32) | (unsigned)bidx[r];
    #pragma unroll
    for (int m = 1; m < 16; m <<= 1) {
      unsigned long long o = __shfl_xor(pk, m, 64);
      pk = (o < pk) ? o : pk;
    }
    if (c16 == 0) s_bd[w * 16 + q * 4 + r] = (int)(pk & 0xffffffffull);
  }
  __syncthreads();

  // fused fin: gather code row, straight-through write (ref rounding), mse, hist
  float se = 0.f;
  {
    int p = tid & 63, cg = tid >> 6;
    int bd = s_bd[p];
    if (cg == 0) atomicAdd(&hist[bd], 1);
    const float* crow = cb + bd * DIM;
    float* ob = out + b * CHW + hw0 + p;
    #pragma unroll 4
    for (int i = 0; i < 16; ++i) {
      int c = cg * 16 + i;
      float xv   = lpf[c][p];          // bit-exact x copy
      float diff = crow[c] - xv;       // nq - x
      se += diff * diff;               // (clean_q - flat)^2 == commit mse
      ob[c * HW] = xv + diff;          // x + stop_grad(nq - x)
    }
  }
  float tot = block_sum(se, scratch);
  if (tid == 0) msep[t] = tot;         // plain store: no atomics, no pre-zero
}

// K2: prep + banded OT dual ascent + scalars (R6 structure) + mse reduce.
__global__ __launch_bounds__(256) void k_ot(const int* __restrict__ hist,
                                            const float* __restrict__ msep,
                                            float* __restrict__ out) {
  __shared__ __align__(16) float s_lt[KCB + 8], s_src[KCB + 8],
                                 s_phi[KCB + 8], s_lse[KCB + 8];
  __shared__ float scratch[4];
  int tid = threadIdx.x;
  int i0  = tid * 4;
  int sl0 = i0 + 4;

  float msetot = block_sum(msep[tid] + msep[tid + 256], scratch);

  int4 hi4 = *(const int4*)(hist + i0);
  int  hi[4] = {hi4.x, hi4.y, hi4.z, hi4.w};
  float tj[4], hj[4];
  #pragma unroll
  for (int j = 0; j < 4; ++j) {
    float fi = (float)(i0 + j);
    float zz = (fi - 511.5f) / (1024.0f / 6.0f);
    tj[j] = expf(-0.5f * zz * zz);
    hj[j] = (float)hi[j] * (1.0f / 32768.0f);
  }
  float St = block_sum(tj[0] + tj[1] + tj[2] + tj[3], scratch);
  float tgt[4], ltw[4];
  float l2 = 0.f;
  #pragma unroll
  for (int j = 0; j < 4; ++j) { tgt[j] = fmaxf(tj[j] / fmaxf(St, 1e-12f), 1e-12f); l2 += tgt[j]; }
  float St2 = block_sum(l2, scratch);
  #pragma unroll
  for (int j = 0; j < 4; ++j) { tgt[j] = tgt[j] / St2; ltw[j] = logf(fmaxf(tgt[j], 1e-12f)); }

  float m1[4], srcw[4];
  float l3 = 0.f;
  #pragma unroll
  for (int j = 0; j < 4; ++j) { m1[j] = fmaxf(hj[j], 1e-12f); l3 += m1[j]; }
  float S1 = block_sum(l3, scratch);
  float l4 = 0.f;
  #pragma unroll
  for (int j = 0; j < 4; ++j) { srcw[j] = fmaxf(m1[j] / S1, 1e-12f); l4 += srcw[j]; }
  float S2 = block_sum(l4, scratch);
  float l5 = 0.f;
  #pragma unroll
  for (int j = 0; j < 4; ++j) { srcw[j] = srcw[j] / S2; l5 += hj[j] * logf(hj[j] + 1e-10f); }
  float ent = block_sum(l5, scratch);

  *(float4*)&s_lt[sl0]  = *(float4*)ltw;
  *(float4*)&s_src[sl0] = *(float4*)srcw;
  *(float4*)&s_phi[sl0] = make_float4(0.f, 0.f, 0.f, 0.f);
  *(float4*)&s_lse[sl0] = make_float4(0.f, 0.f, 0.f, 0.f);
  if (tid == 0) {    // pads: inert (validated R3..R7)
    #pragma unroll
    for (int p = 0; p < 4; ++p) {
      s_lt[p] = -100.f; s_src[p] = 0.f; s_phi[p] = 0.f; s_lse[p] = 0.f;
      s_lt[KCB+4+p] = -100.f; s_src[KCB+4+p] = 0.f; s_phi[KCB+4+p] = 0.f; s_lse[KCB+4+p] = 0.f;
    }
  }
  __syncthreads();

  float ws[12];
  #pragma unroll
  for (int m = 0; m < 3; ++m) *(float4*)&ws[m*4] = *(float4*)&s_src[i0 + m*4];

  float phi[4] = {0.f, 0.f, 0.f, 0.f};
  float lse[4];
  for (int it = 0; it <= 10; ++it) {
    float wl[12], wp[12];
    #pragma unroll
    for (int m = 0; m < 3; ++m) {
      *(float4*)&wl[m*4] = *(float4*)&s_lt[i0 + m*4];
      *(float4*)&wp[m*4] = *(float4*)&s_phi[i0 + m*4];
    }
    #pragma unroll
    for (int j = 0; j < 4; ++j) {
      float mx = -3.0e38f;
      float vv[5];
      #pragma unroll
      for (int qq = 0; qq < 5; ++qq) {
        int m = j + qq + 2;
        float a = wl[m] + (wp[m] - fabsf((float)(qq - 2))) * 20.0f;
        vv[qq] = a;
        mx = fmaxf(mx, a);
      }
      float ssum = 0.f;
      #pragma unroll
      for (int qq = 0; qq < 5; ++qq) ssum += expf(vv[qq] - mx);
      lse[j] = mx + logf(ssum);
    }
    *(float4*)&s_lse[sl0] = *(float4*)lse;
    __syncthreads();
    if (it == 10) break;

    float we[12];
    #pragma unroll
    for (int m = 0; m < 3; ++m) *(float4*)&we[m*4] = *(float4*)&s_lse[i0 + m*4];
    #pragma unroll
    for (int j = 0; j < 4; ++j) {
      float basej = ltw[j] + phi[j] * 20.0f;
      float cs = 0.f;
      #pragma unroll
      for (int qq = 0; qq < 5; ++qq) {
        int m = j + qq + 2;
        float a = basej - fabsf((float)(qq - 2)) * 20.0f;
        cs += ws[m] * expf(a - we[m]);
      }
      phi[j] += 0.5f * (tgt[j] - cs);
    }
    *(float4*)&s_phi[sl0] = *(float4*)phi;
    __syncthreads();
  }

  float lo = 0.f;
  #pragma unroll
  for (int j = 0; j < 4; ++j) lo += srcw[j] * (-0.05f * lse[j]) + tgt[j] * phi[j];
  float ot = block_sum(lo, scratch);

  if (tid == 0) {
    out[2097152] = 1.25f * (msetot * (1.0f / 2097152.0f)) + ot;
    out[2097153] = expf(-ent);
  }
}

extern "C" void kernel_launch(void* const* d_in, const int* in_sizes, int n_in,
                              void* d_out, int out_size, void* d_ws, size_t ws_size,
                              hipStream_t stream) {
  const float* x  = (const float*)d_in[0];   // [32,64,32,32]
  const float* cb = (const float*)d_in[1];   // [1024,64]
  float* out = (float*)d_out;                // quantized(2097152) | loss | perplexity

  unsigned short* cbh = (unsigned short*)d_ws;                      // 128 KB
  unsigned short* cbl = (unsigned short*)((char*)d_ws + 131072);    // 128 KB
  float* cnorm = (float*)((char*)d_ws + 262144);                    // 4 KB
  float* msep  = (float*)((char*)d_ws + 266240);                    // 2 KB
  int*   hist  = (int*)((char*)d_ws + 270336);                      // 4 KB

  k_cvt<<<4, 256, 0, stream>>>(cb, cbh, cbl, cnorm, hist);
  k_dist<<<512, 256, 0, stream>>>(x, cb, cbh, cbl, cnorm, hist, msep, out);
  k_ot<<<1, 256, 0, stream>>>(hist, msep, out);
}

// Round 9
// 131.490 us; speedup vs baseline: 1.2418x; 1.0626x over previous
//
#include <hip/hip_runtime.h>
#include <math.h>

// Problem constants: B=32, C=D=64, H=W=32
#define NPTS 32768      // B*H*W
#define KCB  1024
#define DIM  64
#define HW   1024
#define CHW  65536
#define RWIN 2          // OT band radius (validated R3..R8: absmax 0.0)

typedef short  bf16x8 __attribute__((ext_vector_type(8)));
typedef float  f32x16 __attribute__((ext_vector_type(16)));

__device__ __forceinline__ unsigned short f2b_rne(float f) {
  unsigned u = __float_as_uint(f);
  unsigned r = 0x7FFFu + ((u >> 16) & 1u);
  return (unsigned short)((u + r) >> 16);
}

__device__ __forceinline__ float block_sum(float v, float* scratch) {
  #pragma unroll
  for (int o = 32; o > 0; o >>= 1) v += __shfl_down(v, o, 64);
  int wid  = threadIdx.x >> 6;
  int lane = threadIdx.x & 63;
  __syncthreads();
  if (lane == 0) scratch[wid] = v;
  __syncthreads();
  float s = 0.f;
  int nw = blockDim.x >> 6;
  for (int w = 0; w < nw; ++w) s += scratch[w];
  return s;
}

// K0: codebook -> fragment-ordered bf16 hi/lo global array + cnorm (exact chain).
// cbf chunk layout (f4=16B units): chunk ch (64 codes) at ch*1024;
//   hi frag (nt,s,u,n) at (nt*4+s)*64 + u*32 + n ; lo at +512.
// This makes k_dist staging a LINEAR copy (write quad = tid%8) and MFMA reads
// hit quad = n%8 -> both sides bank-conflict-free by construction.
__global__ __launch_bounds__(64) void k_cvt(const float* __restrict__ cb,
                                            float4* __restrict__ cbf,
                                            float* __restrict__ cnorm) {
  int c = blockIdx.x * 64 + threadIdx.x;   // 16 blocks x 64 = 1024 codes
  const float4* row4 = (const float4*)(cb + c * DIM);
  float4 r[16];
  #pragma unroll
  for (int i = 0; i < 16; ++i) r[i] = row4[i];
  float s = 0.f;
  #pragma unroll
  for (int i = 0; i < 16; ++i) {          // exact f4 fmaf chain (validated rounds)
    s = fmaf(r[i].x, r[i].x, s); s = fmaf(r[i].y, r[i].y, s);
    s = fmaf(r[i].z, r[i].z, s); s = fmaf(r[i].w, r[i].w, s);
  }
  cnorm[c] = s;
  int ch = c >> 6, nt = (c >> 5) & 1, n = c & 31;
  int base = ch * 1024 + nt * 256 + n;
  #pragma unroll
  for (int o = 0; o < 8; ++o) {           // octet o = dims 8o..8o+7
    float f[8] = {r[2*o].x, r[2*o].y, r[2*o].z, r[2*o].w,
                  r[2*o+1].x, r[2*o+1].y, r[2*o+1].z, r[2*o+1].w};
    unsigned hu[4], lu[4];
    #pragma unroll
    for (int j = 0; j < 4; ++j) {
      unsigned short h0 = f2b_rne(f[2*j]),   h1 = f2b_rne(f[2*j+1]);
      float hf0 = __uint_as_float((unsigned)h0 << 16);
      float hf1 = __uint_as_float((unsigned)h1 << 16);
      unsigned short l0 = f2b_rne(f[2*j] - hf0), l1 = f2b_rne(f[2*j+1] - hf1);
      hu[j] = (unsigned)h0 | ((unsigned)h1 << 16);
      lu[j] = (unsigned)l0 | ((unsigned)l1 << 16);
    }
    int pos = base + (o >> 1) * 64 + (o & 1) * 32;   // s = o>>1, u = o&1
    uint4 hv = {hu[0], hu[1], hu[2], hu[3]};
    uint4 lv = {lu[0], lu[1], lu[2], lu[3]};
    cbf[pos]       = *(float4*)&hv;
    cbf[pos + 512] = *(float4*)&lv;
  }
}

// K1: 32x32x16-MFMA distance GEMM + fused fin. 512 blocks x 64 pts, all codes.
// Waves: wm = w>>1 (m-tile of 32 pts), wn = w&1 (n-half of each 64-code chunk).
// Double-buffered LDS chunks, ONE barrier per chunk (lgkm-only wait + raw
// s_barrier: global prefetch stays in flight across it — no vmcnt(0) drain).
__global__ __launch_bounds__(256, 2) void k_dist(const float* __restrict__ x,
                                                 const float* __restrict__ cb,
                                                 const float4* __restrict__ cbf,
                                                 const float* __restrict__ cnorm,
                                                 int* __restrict__ hist,
                                                 float* __restrict__ msep,
                                                 float* __restrict__ out) {
  __shared__ unsigned short lph[64][72], lpl[64][72];  // point bf16 hi/lo rows
  __shared__ short bbuf[2][8192];                      // 2 x 16 KB code-frag chunks
  __shared__ float s_cn[KCB];
  __shared__ float s_sx[64], s_part[4][64];
  __shared__ unsigned long long s_pk[64][2];
  __shared__ int   s_bd[64];
  __shared__ float scratch[4];

  int tid = threadIdx.x;
  int t   = blockIdx.x;
  int n0  = t * 64;
  int b   = n0 >> 10;
  int hw0 = n0 & 1023;

  *(float4*)&s_cn[tid * 4] = *(const float4*)(cnorm + tid * 4);

  // point staging + bf16 hi/lo conversion (R8-validated pattern)
  {
    int p = tid & 63, q4 = tid >> 6;
    const float* xb = x + b * CHW + hw0 + p;
    float s = 0.f;
    unsigned short hb[16], lb[16];
    #pragma unroll
    for (int i = 0; i < 16; ++i) {
      int c = q4 * 16 + i;
      float f = xb[c * HW];
      s = fmaf(f, f, s);
      unsigned short h = f2b_rne(f);
      float hf = __uint_as_float(((unsigned)h) << 16);
      hb[i] = h;
      lb[i] = f2b_rne(f - hf);
    }
    s_part[q4][p] = s;
    #pragma unroll
    for (int j = 0; j < 8; ++j) {
      *(unsigned*)&lph[p][q4 * 16 + 2 * j] = (unsigned)hb[2*j] | ((unsigned)hb[2*j+1] << 16);
      *(unsigned*)&lpl[p][q4 * 16 + 2 * j] = (unsigned)lb[2*j] | ((unsigned)lb[2*j+1] << 16);
    }
  }
  // prefetch chunk 0 (linear f4 copy, 16 VGPRs held — R7 spill lesson)
  float4 pf[4];
  #pragma unroll
  for (int j = 0; j < 4; ++j) pf[j] = cbf[tid + 256 * j];
  __syncthreads();
  if (tid < 64)
    s_sx[tid] = ((s_part[0][tid] + s_part[1][tid]) + s_part[2][tid]) + s_part[3][tid];
  __syncthreads();

  int w = tid >> 6, l = tid & 63;
  int wm = w >> 1, wn = w & 1;
  int u = l >> 5, n = l & 31;

  // A-frags: lane holds A[m=n][k=u*8+j] for k-step s -> octet (2s+u) of point row
  bf16x8 ah[4], al[4];
  {
    int pt = wm * 32 + n;
    #pragma unroll
    for (int s = 0; s < 4; ++s) {
      ah[s] = *(const bf16x8*)&lph[pt][(2 * s + u) * 8];
      al[s] = *(const bf16x8*)&lpl[pt][(2 * s + u) * 8];
    }
  }
  // C/D 32x32 layout: col=lane&31, row=(reg&3)+8*(reg>>2)+4*(lane>>5)  [m74/m101]
  float sxr[16];
  #pragma unroll
  for (int r = 0; r < 16; ++r)
    sxr[r] = s_sx[wm * 32 + (r & 3) + 8 * (r >> 2) + 4 * u];

  float best[16]; int bidx[16];
  #pragma unroll
  for (int r = 0; r < 16; ++r) { best[r] = 3.4e38f; bidx[r] = 0; }

  int bofs = wn * 256 + u * 32 + n;     // f4 base for s=0 hi frag

  for (int ch = 0; ch < 16; ++ch) {
    int bb = ch & 1;
    #pragma unroll
    for (int j = 0; j < 4; ++j)          // linear store: quad = tid%8, conflict-free
      *(float4*)&bbuf[bb][(tid + 256 * j) * 8] = pf[j];
    if (ch < 15) {
      #pragma unroll
      for (int j = 0; j < 4; ++j)
        pf[j] = cbf[(ch + 1) * 1024 + tid + 256 * j];
    }
    __builtin_amdgcn_s_waitcnt(0xc07f);  // lgkmcnt(0) only: ds_writes visible,
    __builtin_amdgcn_s_barrier();        // prefetch loads stay in flight

    f32x16 acc;
    #pragma unroll
    for (int r = 0; r < 16; ++r) acc[r] = 0.f;
    #pragma unroll
    for (int s = 0; s < 4; ++s) {
      bf16x8 bh = *(const bf16x8*)&bbuf[bb][(bofs + s * 64) * 8];
      bf16x8 bl = *(const bf16x8*)&bbuf[bb][(bofs + s * 64 + 512) * 8];
      acc = __builtin_amdgcn_mfma_f32_32x32x16_bf16(ah[s], bh, acc, 0, 0, 0);
      acc = __builtin_amdgcn_mfma_f32_32x32x16_bf16(ah[s], bl, acc, 0, 0, 0);
      acc = __builtin_amdgcn_mfma_f32_32x32x16_bf16(al[s], bh, acc, 0, 0, 0);
    }
    float cnv = s_cn[ch * 64 + wn * 32 + n];
    int   kk  = ch * 64 + wn * 32 + n;
    #pragma unroll
    for (int r = 0; r < 16; ++r) {
      // reference fp32 rounding shape: (||x||^2 + ||c||^2) - 2*x.c
      float dist = (sxr[r] + cnv) - 2.0f * acc[r];
      if (dist < best[r]) { best[r] = dist; bidx[r] = kk; }  // ch asc -> first-min
    }
  }

  // cross-lane argmin within each 32-lane half (cols of the 32x32 tile)
  #pragma unroll
  for (int r = 0; r < 16; ++r) {
    unsigned long long p =
        ((unsigned long long)__float_as_uint(best[r]) << 32) | (unsigned)bidx[r];
    #pragma unroll
    for (int m = 1; m < 32; m <<= 1) {
      unsigned long long o = __shfl_xor(p, m, 64);
      p = (o < p) ? o : p;
    }
    if (n == 0)
      s_pk[wm * 32 + (r & 3) + 8 * (r >> 2) + 4 * u][wn] = p;
  }
  __syncthreads();
  if (tid < 64) {
    unsigned long long a = s_pk[tid][0], c2 = s_pk[tid][1];
    unsigned long long mn = (c2 < a) ? c2 : a;   // tie -> lower idx (half0 < half1)
    int bd = (int)(mn & 0xffffffffull);
    s_bd[tid] = bd;
    atomicAdd(&hist[bd], 1);
  }
  __syncthreads();

  // fused fin: gather code row, straight-through write (ref rounding), mse
  float se = 0.f;
  {
    int p = tid & 63, cg = tid >> 6;
    int bd = s_bd[p];
    const float* crow = cb + bd * DIM;
    const float* xp = x + b * CHW + hw0 + p;
    float* ob = out + b * CHW + hw0 + p;
    #pragma unroll 4
    for (int i = 0; i < 16; ++i) {
      int c = cg * 16 + i;
      float xv   = xp[c * HW];         // exact x (global re-read, coalesced)
      float diff = crow[c] - xv;       // nq - x
      se += diff * diff;               // (clean_q - flat)^2 == commit mse
      ob[c * HW] = xv + diff;          // x + stop_grad(nq - x)
    }
  }
  float tot = block_sum(se, scratch);
  if (tid == 0) msep[t] = tot;         // plain store: no atomics, no pre-zero
}

// K2: prep + banded OT dual ascent + scalars (R8 structure, unchanged).
__global__ __launch_bounds__(256) void k_ot(const int* __restrict__ hist,
                                            const float* __restrict__ msep,
                                            float* __restrict__ out) {
  __shared__ __align__(16) float s_lt[KCB + 8], s_src[KCB + 8],
                                 s_phi[KCB + 8], s_lse[KCB + 8];
  __shared__ float scratch[4];
  int tid = threadIdx.x;
  int i0  = tid * 4;
  int sl0 = i0 + 4;

  float msetot = block_sum(msep[tid] + msep[tid + 256], scratch);

  int4 hi4 = *(const int4*)(hist + i0);
  int  hi[4] = {hi4.x, hi4.y, hi4.z, hi4.w};
  float tj[4], hj[4];
  #pragma unroll
  for (int j = 0; j < 4; ++j) {
    float fi = (float)(i0 + j);
    float zz = (fi - 511.5f) / (1024.0f / 6.0f);
    tj[j] = expf(-0.5f * zz * zz);
    hj[j] = (float)hi[j] * (1.0f / 32768.0f);
  }
  float St = block_sum(tj[0] + tj[1] + tj[2] + tj[3], scratch);
  float tgt[4], ltw[4];
  float l2 = 0.f;
  #pragma unroll
  for (int j = 0; j < 4; ++j) { tgt[j] = fmaxf(tj[j] / fmaxf(St, 1e-12f), 1e-12f); l2 += tgt[j]; }
  float St2 = block_sum(l2, scratch);
  #pragma unroll
  for (int j = 0; j < 4; ++j) { tgt[j] = tgt[j] / St2; ltw[j] = logf(fmaxf(tgt[j], 1e-12f)); }

  float m1[4], srcw[4];
  float l3 = 0.f;
  #pragma unroll
  for (int j = 0; j < 4; ++j) { m1[j] = fmaxf(hj[j], 1e-12f); l3 += m1[j]; }
  float S1 = block_sum(l3, scratch);
  float l4 = 0.f;
  #pragma unroll
  for (int j = 0; j < 4; ++j) { srcw[j] = fmaxf(m1[j] / S1, 1e-12f); l4 += srcw[j]; }
  float S2 = block_sum(l4, scratch);
  float l5 = 0.f;
  #pragma unroll
  for (int j = 0; j < 4; ++j) { srcw[j] = srcw[j] / S2; l5 += hj[j] * logf(hj[j] + 1e-10f); }
  float ent = block_sum(l5, scratch);

  *(float4*)&s_lt[sl0]  = *(float4*)ltw;
  *(float4*)&s_src[sl0] = *(float4*)srcw;
  *(float4*)&s_phi[sl0] = make_float4(0.f, 0.f, 0.f, 0.f);
  *(float4*)&s_lse[sl0] = make_float4(0.f, 0.f, 0.f, 0.f);
  if (tid == 0) {    // pads: inert (validated R3..R8)
    #pragma unroll
    for (int p = 0; p < 4; ++p) {
      s_lt[p] = -100.f; s_src[p] = 0.f; s_phi[p] = 0.f; s_lse[p] = 0.f;
      s_lt[KCB+4+p] = -100.f; s_src[KCB+4+p] = 0.f; s_phi[KCB+4+p] = 0.f; s_lse[KCB+4+p] = 0.f;
    }
  }
  __syncthreads();

  float ws[12];
  #pragma unroll
  for (int m = 0; m < 3; ++m) *(float4*)&ws[m*4] = *(float4*)&s_src[i0 + m*4];

  float phi[4] = {0.f, 0.f, 0.f, 0.f};
  float lse[4];
  for (int it = 0; it <= 10; ++it) {
    float wl[12], wp[12];
    #pragma unroll
    for (int m = 0; m < 3; ++m) {
      *(float4*)&wl[m*4] = *(float4*)&s_lt[i0 + m*4];
      *(float4*)&wp[m*4] = *(float4*)&s_phi[i0 + m*4];
    }
    #pragma unroll
    for (int j = 0; j < 4; ++j) {
      float mx = -3.0e38f;
      float vv[5];
      #pragma unroll
      for (int qq = 0; qq < 5; ++qq) {
        int m = j + qq + 2;
        float a = wl[m] + (wp[m] - fabsf((float)(qq - 2))) * 20.0f;
        vv[qq] = a;
        mx = fmaxf(mx, a);
      }
      float ssum = 0.f;
      #pragma unroll
      for (int qq = 0; qq < 5; ++qq) ssum += expf(vv[qq] - mx);
      lse[j] = mx + logf(ssum);
    }
    *(float4*)&s_lse[sl0] = *(float4*)lse;
    __syncthreads();
    if (it == 10) break;

    float we[12];
    #pragma unroll
    for (int m = 0; m < 3; ++m) *(float4*)&we[m*4] = *(float4*)&s_lse[i0 + m*4];
    #pragma unroll
    for (int j = 0; j < 4; ++j) {
      float basej = ltw[j] + phi[j] * 20.0f;
      float cs = 0.f;
      #pragma unroll
      for (int qq = 0; qq < 5; ++qq) {
        int m = j + qq + 2;
        float a = basej - fabsf((float)(qq - 2)) * 20.0f;
        cs += ws[m] * expf(a - we[m]);
      }
      phi[j] += 0.5f * (tgt[j] - cs);
    }
    *(float4*)&s_phi[sl0] = *(float4*)phi;
    __syncthreads();
  }

  float lo = 0.f;
  #pragma unroll
  for (int j = 0; j < 4; ++j) lo += srcw[j] * (-0.05f * lse[j]) + tgt[j] * phi[j];
  float ot = block_sum(lo, scratch);

  if (tid == 0) {
    out[2097152] = 1.25f * (msetot * (1.0f / 2097152.0f)) + ot;
    out[2097153] = expf(-ent);
  }
}

extern "C" void kernel_launch(void* const* d_in, const int* in_sizes, int n_in,
                              void* d_out, int out_size, void* d_ws, size_t ws_size,
                              hipStream_t stream) {
  const float* x  = (const float*)d_in[0];   // [32,64,32,32]
  const float* cb = (const float*)d_in[1];   // [1024,64]
  float* out = (float*)d_out;                // quantized(2097152) | loss | perplexity

  float4* cbf  = (float4*)d_ws;                        // 256 KB fragment-ordered codes
  float*  cnorm = (float*)((char*)d_ws + 262144);      // 4 KB
  int*    hist  = (int*)((char*)d_ws + 266240);        // 4 KB
  float*  msep  = (float*)((char*)d_ws + 270336);      // 2 KB

  hipMemsetAsync(hist, 0, 4096, stream);
  k_cvt<<<16, 64, 0, stream>>>(cb, cbf, cnorm);
  k_dist<<<512, 256, 0, stream>>>(x, cb, cbf, cnorm, hist, msep, out);
  k_ot<<<1, 256, 0, stream>>>(hist, msep, out);
}